// Round 1
// 102.829 us; speedup vs baseline: 1.0237x; 1.0237x over previous
//
#include <hip/hip_runtime.h>
#include <hip/hip_bf16.h>
#include <math.h>

// PhaseMLP fully fused: interp-then-matmul == GEMM with c-scaled A:
//   y[b,o] = sum_{k,i} (c_k(b)*x[b,i]) * Wflat[k*K+i, o]
// One block carries its 16 rows through all 3 layers, activations in LDS.
// R4 change vs R3: B-gather pipeline deepened 4->8, and prefetch issue is
// hoisted ACROSS layer boundaries: layer-(N+1)'s first 8 loads are issued
// before layer-N's epilogue+barrier (epilogue VALU + LDS writes hide the
// ~200cy L2 hit latency), and layer-0's prefetch is issued before the A0
// build (hidden under the x HBM load + build + barrier). Bias values are
// preloaded before each GEMM loop. Accumulation order unchanged -> same
// numerics as R3 (absmax 0.0625).

typedef __attribute__((ext_vector_type(8))) short bf16x8;
typedef __attribute__((ext_vector_type(4))) float f32x4;

#define STRIDE 2048  // bytes per LDS A-row: 128 segs x 16B (A0 uses 64 segs)
#define PFD 8        // B prefetch pipeline depth (power of 2)

static __device__ __forceinline__ unsigned short f2bf(float f) {
  union { float f; unsigned int u; } v; v.f = f;
  unsigned int r = v.u + 0x7fffu + ((v.u >> 16) & 1u);  // RNE
  return (unsigned short)(r >> 16);
}

// Catmull-Rom basis coeffs in ABSOLUTE anchor order (c[0..3] for anchors 0..3)
static __device__ __forceinline__ void catmull(float ph, float c[4]) {
  float t = 4.0f * ph;
  float ft = floorf(t);
  int i1 = ((int)ft) & 3;
  float w = t - ft;
  float w2 = w * w, w3 = w2 * w;
  float r0 = -0.5f * w + w2 - 0.5f * w3;
  float r1 = 1.0f - 2.5f * w2 + 1.5f * w3;
  float r2 = 0.5f * w + 2.0f * w2 - 1.5f * w3;
  float r3 = -0.5f * w2 + 0.5f * w3;
  c[(i1 + 3) & 3] = r0;
  c[i1]           = r1;
  c[(i1 + 1) & 3] = r2;
  c[(i1 + 2) & 3] = r3;
}

// ---------------------------------------------------------------------------
// Prep: transpose+convert all three weight tensors (fp32 [4K,O] -> bf16 [O,4K])
// ---------------------------------------------------------------------------
__global__ void k_wt_all(const float* __restrict__ w0, const float* __restrict__ w1,
                         const float* __restrict__ w2, unsigned short* __restrict__ t0,
                         unsigned short* __restrict__ t1, unsigned short* __restrict__ t2) {
  __shared__ float tile[32][33];
  int bid = blockIdx.x;
  const float* W; unsigned short* T; int R, C, idx;
  if (bid < 128)      { W = w0; T = t0; R = 512;  C = 256; idx = bid; }
  else if (bid < 384) { W = w1; T = t1; R = 1024; C = 256; idx = bid - 128; }
  else                { W = w2; T = t2; R = 1024; C = 128; idx = bid - 384; }
  int ntc = C >> 5;
  int tr = (idx / ntc) << 5;
  int tc = (idx % ntc) << 5;
  int tx = threadIdx.x, ty = threadIdx.y;  // (32,8)
#pragma unroll
  for (int j = ty; j < 32; j += 8)
    tile[j][tx] = W[(size_t)(tr + j) * C + (tc + tx)];
  __syncthreads();
#pragma unroll
  for (int j = ty; j < 32; j += 8)
    T[(size_t)(tc + j) * R + (tr + tx)] = f2bf(tile[tx][j]);
}

// ---------------------------------------------------------------------------
// B prefetch: issue PFD loads into the rotating register pipeline.
// ---------------------------------------------------------------------------
static __device__ __forceinline__ void b_pre(const unsigned short* __restrict__ bp,
                                             bf16x8 (&pre)[PFD]) {
#pragma unroll
  for (int i = 0; i < PFD; ++i) pre[i] = *(const bf16x8*)(bp + i * 32);
}

// Inner GEMM loop consuming the depth-PFD pipeline (pre must already hold the
// first PFD chunks of bp). abase = bufIn + col*STRIDE (XOR-swizzled A rows).
template <int NC>
static __device__ __forceinline__ f32x4 gemm_run(const char* abase,
                                                 const unsigned short* __restrict__ bp,
                                                 bf16x8 (&pre)[PFD],
                                                 int xr, int quad, int ck0) {
  f32x4 acc = (f32x4){0.f, 0.f, 0.f, 0.f};
#pragma unroll
  for (int i = 0; i < NC; ++i) {
    bf16x8 bv = pre[i & (PFD - 1)];
    if (i + PFD < NC) pre[i & (PFD - 1)] = *(const bf16x8*)(bp + (i + PFD) * 32);
    int s = (ck0 + i) * 4 + quad;
    bf16x8 av = *(const bf16x8*)(abase + ((s ^ xr) << 4));
    acc = __builtin_amdgcn_mfma_f32_16x16x32_bf16(av, bv, acc, 0, 0, 0);
  }
  return acc;
}

// epilogue for layers 0/1: bias-mix, ELU, write 4 c-scaled bf16 copies to bufOut
static __device__ __forceinline__ void epi_mid(f32x4 acc, float bv0, float bv1,
                                               float bv2, float bv3, int N, int colg,
                                               int quad, const float cb[4][4],
                                               char* bufOut) {
#pragma unroll
  for (int r = 0; r < 4; ++r) {
    int m = quad * 4 + r;
    float v = acc[r] + cb[r][0] * bv0 + cb[r][1] * bv1 + cb[r][2] * bv2 + cb[r][3] * bv3;
    float a = v > 0.0f ? v : (__expf(v) - 1.0f);  // ELU
#pragma unroll
    for (int k = 0; k < 4; ++k) {
      int idx = k * N + colg;
      int s = idx >> 3, j = idx & 7;
      *(unsigned short*)(bufOut + m * STRIDE + ((s ^ (m & 7)) << 4) + j * 2) =
          f2bf(cb[r][k] * a);
    }
  }
}

__global__ __launch_bounds__(1024, 4) void k_fused(
    const float* __restrict__ x, const float* __restrict__ phase,
    const unsigned short* __restrict__ Wt0, const float* __restrict__ b0,
    const unsigned short* __restrict__ Wt1, const float* __restrict__ b1,
    const unsigned short* __restrict__ Wt2, const float* __restrict__ b2,
    float* __restrict__ out) {
  __shared__ __align__(16) char bufA[16 * STRIDE];  // A0 / A2
  __shared__ __align__(16) char bufB[16 * STRIDE];  // A1, then layer-2 reduce buf

  const int tid = threadIdx.x;
  const int lane = tid & 63;
  const int wid = tid >> 6;     // 0..15
  const int col = lane & 15;
  const int quad = lane >> 4;
  const int xr = col & 7;
  const int m0 = blockIdx.x * 16;
  const int colg0 = wid * 16 + col;
  const int colbase = (wid & 7) * 16;
  const int kh = wid >> 3;
  const int colg2 = colbase + col;

  const unsigned short* bp0 = Wt0 + (size_t)colg0 * 512 + quad * 8;
  const unsigned short* bp1 = Wt1 + (size_t)colg0 * 1024 + quad * 8;
  const unsigned short* bp2 = Wt2 + (size_t)colg2 * 1024 + (size_t)kh * 512 + quad * 8;

  // ---- issue x loads, then L0 B prefetch, BEFORE any dependent math ----
  const int am = tid >> 6;   // A0-build row 0..15
  const int as = tid & 63;   // 16B segment within row
  const float* xp = x + (size_t)(m0 + am) * 128 + ((as & 15) << 3);
  float4 xa = *(const float4*)xp;
  float4 xbv = *(const float4*)(xp + 4);
  float aph = phase[m0 + am];

  bf16x8 pre[PFD];
  b_pre(bp0, pre);   // in flight under A0 build + barrier

  // per-lane Catmull coeffs for its 4 accumulator rows (m = quad*4+r)
  float cb[4][4];
#pragma unroll
  for (int r = 0; r < 4; ++r) catmull(phase[m0 + quad * 4 + r], cb[r]);

  // ---- build A0 (c-scaled bf16 x) into bufA: 16 rows x 64 segs = 1024 thr ----
  {
    float cr[4];
    catmull(aph, cr);
    float cv = cr[as >> 4];
    bf16x8 v;
    v[0] = (short)f2bf(cv * xa.x);  v[1] = (short)f2bf(cv * xa.y);
    v[2] = (short)f2bf(cv * xa.z);  v[3] = (short)f2bf(cv * xa.w);
    v[4] = (short)f2bf(cv * xbv.x); v[5] = (short)f2bf(cv * xbv.y);
    v[6] = (short)f2bf(cv * xbv.z); v[7] = (short)f2bf(cv * xbv.w);
    *(bf16x8*)(bufA + am * STRIDE + ((as ^ (am & 7)) << 4)) = v;
  }
  __syncthreads();

  // ---- layer 0: bufA (K=512) @ Wt0 -> bufB (A1), 16 waves x 16 cols
  {
    float bv0 = b0[colg0], bv1 = b0[256 + colg0], bv2 = b0[512 + colg0],
          bv3 = b0[768 + colg0];
    f32x4 acc = gemm_run<16>(bufA + col * STRIDE, bp0, pre, xr, quad, 0);
    b_pre(bp1, pre);   // L1 prefetch hides under epilogue + barrier
    epi_mid(acc, bv0, bv1, bv2, bv3, 256, colg0, quad, cb, bufB);
  }
  __syncthreads();

  // ---- layer 1: bufB (K=1024) @ Wt1 -> bufA (A2)
  {
    float bv0 = b1[colg0], bv1 = b1[256 + colg0], bv2 = b1[512 + colg0],
          bv3 = b1[768 + colg0];
    f32x4 acc = gemm_run<32>(bufB + col * STRIDE, bp1, pre, xr, quad, 0);
    b_pre(bp2, pre);   // L2 prefetch hides under epilogue + barrier
    epi_mid(acc, bv0, bv1, bv2, bv3, 256, colg0, quad, cb, bufA);
  }
  __syncthreads();

  // ---- layer 2: bufA (K=1024) @ Wt2 -> out fp32. N=128: 8 col-grps x 2 k-halves
  {
    float bv0 = b2[colg2], bv1 = b2[128 + colg2], bv2 = b2[256 + colg2],
          bv3 = b2[384 + colg2];
    f32x4 acc = gemm_run<16>(bufA + col * STRIDE, bp2, pre, xr, quad, kh * 16);

    float* red = (float*)bufB;  // [8][16][17] fp32, overlaid (A1 is dead)
    if (wid >= 8) {
#pragma unroll
      for (int r = 0; r < 4; ++r)
        red[(wid - 8) * 272 + (quad * 4 + r) * 17 + col] = acc[r];
    }
    __syncthreads();
    if (wid < 8) {
#pragma unroll
      for (int r = 0; r < 4; ++r) {
        float v = acc[r] + red[wid * 272 + (quad * 4 + r) * 17 + col];
        v += cb[r][0] * bv0 + cb[r][1] * bv1 + cb[r][2] * bv2 + cb[r][3] * bv3;
        out[(size_t)(m0 + quad * 4 + r) * 128 + colg2] = v;
      }
    }
  }
}

// ---------------------------------------------------------------------------
// ws layout: Wt0 @0 (256KB), Wt1 @256KB (512KB), Wt2 @768KB (256KB). 1 MB.
// ---------------------------------------------------------------------------
extern "C" void kernel_launch(void* const* d_in, const int* in_sizes, int n_in,
                              void* d_out, int out_size, void* d_ws, size_t ws_size,
                              hipStream_t stream) {
  const float* x     = (const float*)d_in[0];
  const float* phase = (const float*)d_in[1];
  const float* w0    = (const float*)d_in[2];
  const float* b0    = (const float*)d_in[3];
  const float* w1    = (const float*)d_in[4];
  const float* b1    = (const float*)d_in[5];
  const float* w2    = (const float*)d_in[6];
  const float* b2    = (const float*)d_in[7];
  float* out = (float*)d_out;

  char* ws = (char*)d_ws;
  unsigned short* Wt0 = (unsigned short*)ws;
  unsigned short* Wt1 = (unsigned short*)(ws + 262144);
  unsigned short* Wt2 = (unsigned short*)(ws + 262144 + 524288);

  k_wt_all<<<512, dim3(32, 8), 0, stream>>>(w0, w1, w2, Wt0, Wt1, Wt2);
  k_fused<<<256, 1024, 0, stream>>>(x, phase, Wt0, b0, Wt1, b1, Wt2, b2, out);
}

// Round 2
// 101.544 us; speedup vs baseline: 1.0366x; 1.0126x over previous
//
#include <hip/hip_runtime.h>
#include <hip/hip_bf16.h>
#include <math.h>

// PhaseMLP fused, R5: anchor-split GEMM.
//   y[b,o] = sum_k c_k(b) * ( x[b,:] @ W_k + b_k )   (Catmull-Rom is linear)
// A (activations) stored ONCE, unscaled bf16 in LDS; 4 anchor GEMMs share
// each A fragment (1 ds_read feeds 4 MFMAs); anchor-combine with per-row
// c_k happens on fp32 accumulators in the epilogue (c table in LDS).
// LDS per row drops 4x -> M=32 rows/block in 58KB static LDS, grid=128:
// per-block weight traffic (1MB from L2) now serves 32 rows -> total L2
// weight reads halve (256MB -> 128MB). Per-wave: 2 M-tiles reuse each bv.
// B pipeline: rotating 3-iteration (12 loads, imm offsets off one base).
// Cross-layer prefetch hoist retained from R4.

typedef __attribute__((ext_vector_type(8))) short bf16x8;
typedef __attribute__((ext_vector_type(4))) float f32x4;

#define PF 3  // B prefetch depth in iterations (4 loads each)

static __device__ __forceinline__ unsigned short f2bf(float f) {
  union { float f; unsigned int u; } v; v.f = f;
  unsigned int r = v.u + 0x7fffu + ((v.u >> 16) & 1u);  // RNE
  return (unsigned short)(r >> 16);
}

// Catmull-Rom basis coeffs in ABSOLUTE anchor order (c[0..3] for anchors 0..3)
static __device__ __forceinline__ void catmull(float ph, float c[4]) {
  float t = 4.0f * ph;
  float ft = floorf(t);
  int i1 = ((int)ft) & 3;
  float w = t - ft;
  float w2 = w * w, w3 = w2 * w;
  float r0 = -0.5f * w + w2 - 0.5f * w3;
  float r1 = 1.0f - 2.5f * w2 + 1.5f * w3;
  float r2 = 0.5f * w + 2.0f * w2 - 1.5f * w3;
  float r3 = -0.5f * w2 + 0.5f * w3;
  c[(i1 + 3) & 3] = r0;
  c[i1]           = r1;
  c[(i1 + 1) & 3] = r2;
  c[(i1 + 2) & 3] = r3;
}

// ---------------------------------------------------------------------------
// Prep: transpose+convert all three weight tensors (fp32 [4K,O] -> bf16 [O,4K])
// ---------------------------------------------------------------------------
__global__ void k_wt_all(const float* __restrict__ w0, const float* __restrict__ w1,
                         const float* __restrict__ w2, unsigned short* __restrict__ t0,
                         unsigned short* __restrict__ t1, unsigned short* __restrict__ t2) {
  __shared__ float tile[32][33];
  int bid = blockIdx.x;
  const float* W; unsigned short* T; int R, C, idx;
  if (bid < 128)      { W = w0; T = t0; R = 512;  C = 256; idx = bid; }
  else if (bid < 384) { W = w1; T = t1; R = 1024; C = 256; idx = bid - 128; }
  else                { W = w2; T = t2; R = 1024; C = 128; idx = bid - 384; }
  int ntc = C >> 5;
  int tr = (idx / ntc) << 5;
  int tc = (idx % ntc) << 5;
  int tx = threadIdx.x, ty = threadIdx.y;  // (32,8)
#pragma unroll
  for (int j = ty; j < 32; j += 8)
    tile[j][tx] = W[(size_t)(tr + j) * C + (tc + tx)];
  __syncthreads();
#pragma unroll
  for (int j = ty; j < 32; j += 8)
    T[(size_t)(tc + j) * R + (tr + tx)] = f2bf(tile[tx][j]);
}

// ---------------------------------------------------------------------------
// B prefetch: fill PF iterations (4 anchor loads each), imm offsets off bp.
// KIN = shorts per anchor row in Wt (128 for L0, 256 for L1/L2).
// ---------------------------------------------------------------------------
template <int KIN>
static __device__ __forceinline__ void b_pre(const unsigned short* __restrict__ bp,
                                             bf16x8 (&pre)[PF][4]) {
#pragma unroll
  for (int j = 0; j < PF; ++j)
#pragma unroll
    for (int k = 0; k < 4; ++k)
      pre[j][k] = *(const bf16x8*)(bp + k * KIN + j * 32);
}

// Anchor-split GEMM: NI chunks of K=32; per chunk 2 A-tiles x 4 anchors = 8 MFMA.
// aL0/aL1: per-lane swizzled LDS base for M-tile 0/1; off = (i<<6)^hi16.
template <int NI, int KIN>
static __device__ __forceinline__ void gemm4(const char* aL0, const char* aL1,
                                             int hi16,
                                             const unsigned short* __restrict__ bp,
                                             bf16x8 (&pre)[PF][4],
                                             f32x4 (&acc)[2][4]) {
#pragma unroll
  for (int i = 0; i < NI; ++i) {
    const int off = (i << 6) ^ hi16;
    bf16x8 a0 = *(const bf16x8*)(aL0 + off);
    bf16x8 a1 = *(const bf16x8*)(aL1 + off);
    bf16x8 b0 = pre[i % PF][0];
    bf16x8 b1 = pre[i % PF][1];
    bf16x8 b2 = pre[i % PF][2];
    bf16x8 b3 = pre[i % PF][3];
    if (i + PF < NI) {
#pragma unroll
      for (int k = 0; k < 4; ++k)
        pre[i % PF][k] = *(const bf16x8*)(bp + k * KIN + (i + PF) * 32);
    }
    acc[0][0] = __builtin_amdgcn_mfma_f32_16x16x32_bf16(a0, b0, acc[0][0], 0, 0, 0);
    acc[0][1] = __builtin_amdgcn_mfma_f32_16x16x32_bf16(a0, b1, acc[0][1], 0, 0, 0);
    acc[0][2] = __builtin_amdgcn_mfma_f32_16x16x32_bf16(a0, b2, acc[0][2], 0, 0, 0);
    acc[0][3] = __builtin_amdgcn_mfma_f32_16x16x32_bf16(a0, b3, acc[0][3], 0, 0, 0);
    acc[1][0] = __builtin_amdgcn_mfma_f32_16x16x32_bf16(a1, b0, acc[1][0], 0, 0, 0);
    acc[1][1] = __builtin_amdgcn_mfma_f32_16x16x32_bf16(a1, b1, acc[1][1], 0, 0, 0);
    acc[1][2] = __builtin_amdgcn_mfma_f32_16x16x32_bf16(a1, b2, acc[1][2], 0, 0, 0);
    acc[1][3] = __builtin_amdgcn_mfma_f32_16x16x32_bf16(a1, b3, acc[1][3], 0, 0, 0);
  }
}

// Mid-layer epilogue: anchor-combine (c from LDS table), bias-mix, ELU,
// single unscaled bf16 write per (row,col) to the next A buffer (512B rows).
static __device__ __forceinline__ void epi_mid(f32x4 (&acc)[2][4],
                                               const float bv[4],
                                               const float (*cb)[4],
                                               int colg, int quad, char* bufOut) {
  const int g = colg >> 3;
  const int j2 = (colg & 7) * 2;
#pragma unroll
  for (int t = 0; t < 2; ++t)
#pragma unroll
    for (int r = 0; r < 4; ++r) {
      const int m = t * 16 + quad * 4 + r;
      const float4 c = *(const float4*)cb[m];
      float y = c.x * (acc[t][0][r] + bv[0]) + c.y * (acc[t][1][r] + bv[1]) +
                c.z * (acc[t][2][r] + bv[2]) + c.w * (acc[t][3][r] + bv[3]);
      float a = y > 0.0f ? y : (__expf(y) - 1.0f);  // ELU
      *(unsigned short*)(bufOut + m * 512 + (((g ^ (m & 15)) << 4) + j2)) = f2bf(a);
    }
}

__global__ __launch_bounds__(1024, 4) void k_fused(
    const float* __restrict__ x, const float* __restrict__ phase,
    const unsigned short* __restrict__ Wt0, const float* __restrict__ b0,
    const unsigned short* __restrict__ Wt1, const float* __restrict__ b1,
    const unsigned short* __restrict__ Wt2, const float* __restrict__ b2,
    float* __restrict__ out) {
  __shared__ __align__(16) char A0[32 * 256];   // 8KB, K=128 bf16, swizzled
  __shared__ __align__(16) char A1[32 * 512];   // 16KB
  __shared__ __align__(16) char A2[32 * 512];   // 16KB
  __shared__ float cbuf[32][4];                 // per-row Catmull coeffs
  __shared__ float red[8][32][17];              // L2 K-split reduce (17KB)

  const int tid = threadIdx.x;
  const int lane = tid & 63;
  const int wid = tid >> 6;     // 0..15
  const int col = lane & 15;
  const int quad = lane >> 4;
  const int m0 = blockIdx.x * 32;
  const int colg = wid * 16 + col;
  const int hi16 = (col & 12) << 4;           // high part of granule XOR
  const int lb = (quad ^ (col & 3)) << 4;     // low part folded into base
  const int cg = wid & 7, kh = wid >> 3;
  const int colg2 = cg * 16 + col;

  const unsigned short* bp0 = Wt0 + (size_t)colg * 512 + quad * 8;
  const unsigned short* bp1 = Wt1 + (size_t)colg * 1024 + quad * 8;
  const unsigned short* bp2 = Wt2 + (size_t)colg2 * 1024 + kh * 128 + quad * 8;

  // ---- issue x loads + L0 B prefetch + bias0 before any dependent math ----
  const int arow = tid >> 5;   // 0..31
  const int aseg = tid & 31;   // 4 fp32 each
  const float4 xv = *(const float4*)(x + (size_t)(m0 + arow) * 128 + aseg * 4);

  bf16x8 pre[PF][4];
  b_pre<128>(bp0, pre);        // in flight under A0 build + barrier

  float bvA[4], bvB[4];
#pragma unroll
  for (int k = 0; k < 4; ++k) bvA[k] = b0[k * 256 + colg];

  // per-row Catmull coeff table
  if (tid < 32) {
    float c[4];
    catmull(phase[m0 + tid], c);
    cbuf[tid][0] = c[0]; cbuf[tid][1] = c[1];
    cbuf[tid][2] = c[2]; cbuf[tid][3] = c[3];
  }

  // ---- build A0: unscaled bf16 x, granule-swizzled (g ^ (row&15)) ----
  {
    const int g = aseg >> 1;
    char* p = A0 + arow * 256 + (((g ^ (arow & 15)) << 4) + (aseg & 1) * 8);
    short4 h;
    h.x = (short)f2bf(xv.x); h.y = (short)f2bf(xv.y);
    h.z = (short)f2bf(xv.z); h.w = (short)f2bf(xv.w);
    *(short4*)p = h;
  }
  __syncthreads();

  // ---- layer 0: A0 (K=128 x 4 anchors) @ Wt0 -> A1 ----
  {
    f32x4 acc[2][4];
#pragma unroll
    for (int t = 0; t < 2; ++t)
#pragma unroll
      for (int k = 0; k < 4; ++k) acc[t][k] = (f32x4){0.f, 0.f, 0.f, 0.f};
    gemm4<4, 128>(A0 + col * 256 + lb, A0 + (16 + col) * 256 + lb, hi16, bp0, pre, acc);
    b_pre<256>(bp1, pre);  // L1 prefetch hides under epilogue + barrier
#pragma unroll
    for (int k = 0; k < 4; ++k) bvB[k] = b1[k * 256 + colg];
    epi_mid(acc, bvA, cbuf, colg, quad, A1);
  }
  __syncthreads();

  // ---- layer 1: A1 (K=256 x 4 anchors) @ Wt1 -> A2 ----
  {
    f32x4 acc[2][4];
#pragma unroll
    for (int t = 0; t < 2; ++t)
#pragma unroll
      for (int k = 0; k < 4; ++k) acc[t][k] = (f32x4){0.f, 0.f, 0.f, 0.f};
    gemm4<8, 256>(A1 + col * 512 + lb, A1 + (16 + col) * 512 + lb, hi16, bp1, pre, acc);
    b_pre<256>(bp2, pre);  // L2 prefetch hides under epilogue + barrier
#pragma unroll
    for (int k = 0; k < 4; ++k) bvA[k] = b2[k * 128 + colg2];
    epi_mid(acc, bvB, cbuf, colg, quad, A2);
  }
  __syncthreads();

  // ---- layer 2: A2 (K=256 x 4 anchors) @ Wt2 -> out fp32.
  //      N=128: 8 col-groups x 2 K-halves; kh folded into bp2/aL bases. ----
  {
    f32x4 acc[2][4];
#pragma unroll
    for (int t = 0; t < 2; ++t)
#pragma unroll
      for (int k = 0; k < 4; ++k) acc[t][k] = (f32x4){0.f, 0.f, 0.f, 0.f};
    const char* aL0 = A2 + col * 512 + kh * 256 + lb;
    const char* aL1 = A2 + (16 + col) * 512 + kh * 256 + lb;
    gemm4<4, 256>(aL0, aL1, hi16, bp2, pre, acc);

    float part[2][4];
#pragma unroll
    for (int t = 0; t < 2; ++t)
#pragma unroll
      for (int r = 0; r < 4; ++r) {
        const int m = t * 16 + quad * 4 + r;
        const float4 c = *(const float4*)cbuf[m];
        part[t][r] = c.x * acc[t][0][r] + c.y * acc[t][1][r] +
                     c.z * acc[t][2][r] + c.w * acc[t][3][r];
      }
    if (kh) {
#pragma unroll
      for (int t = 0; t < 2; ++t)
#pragma unroll
        for (int r = 0; r < 4; ++r)
          red[cg][t * 16 + quad * 4 + r][col] = part[t][r];
    }
    __syncthreads();
    if (!kh) {
#pragma unroll
      for (int t = 0; t < 2; ++t)
#pragma unroll
        for (int r = 0; r < 4; ++r) {
          const int m = t * 16 + quad * 4 + r;
          const float4 c = *(const float4*)cbuf[m];
          float y = part[t][r] + red[cg][m][col] +
                    c.x * bvA[0] + c.y * bvA[1] + c.z * bvA[2] + c.w * bvA[3];
          out[(size_t)(m0 + m) * 128 + colg2] = y;
        }
    }
  }
}

// ---------------------------------------------------------------------------
// ws layout: Wt0 @0 (256KB), Wt1 @256KB (512KB), Wt2 @768KB (256KB). 1 MB.
// ---------------------------------------------------------------------------
extern "C" void kernel_launch(void* const* d_in, const int* in_sizes, int n_in,
                              void* d_out, int out_size, void* d_ws, size_t ws_size,
                              hipStream_t stream) {
  const float* x     = (const float*)d_in[0];
  const float* phase = (const float*)d_in[1];
  const float* w0    = (const float*)d_in[2];
  const float* b0    = (const float*)d_in[3];
  const float* w1    = (const float*)d_in[4];
  const float* b1    = (const float*)d_in[5];
  const float* w2    = (const float*)d_in[6];
  const float* b2    = (const float*)d_in[7];
  float* out = (float*)d_out;

  char* ws = (char*)d_ws;
  unsigned short* Wt0 = (unsigned short*)ws;
  unsigned short* Wt1 = (unsigned short*)(ws + 262144);
  unsigned short* Wt2 = (unsigned short*)(ws + 262144 + 524288);

  k_wt_all<<<512, dim3(32, 8), 0, stream>>>(w0, w1, w2, Wt0, Wt1, Wt2);
  k_fused<<<128, 1024, 0, stream>>>(x, phase, Wt0, b0, Wt1, b1, Wt2, b2, out);
}

// Round 3
// 88.657 us; speedup vs baseline: 1.1873x; 1.1454x over previous
//
#include <hip/hip_runtime.h>
#include <hip/hip_bf16.h>
#include <math.h>

// PhaseMLP fused, R6: anchor-split GEMM + vmcnt-counted async B-staging.
//   y[b,o] = sum_k c_k(b) * ( x[b,:] @ W_k + b_k )
// R5 post-mortem: reg-prefetch held only ~3KB/CU in flight -> 10 B/cy L2
// stream (Little's law; measured 10.4). R6 streams weights global->LDS via
// __builtin_amdgcn_global_load_lds (no VGPR cost), per-wave private 4KB
// chunks, double-buffered, counted s_waitcnt vmcnt(4) per chunk, NO barrier
// in the K-loop. Layer boundaries use raw s_barrier + lgkmcnt(0) only, so
// the B-stream stays in flight across layers. 256 blocks x M=16 rows (all
// CUs busy). LDS B-chunk layout = dense [anchor][1024B] per wave: the
// lane->granule permutation is folded into the per-lane GLOBAL source
// address (global_load_lds writes base+lane*16 linearly); ds_read_b128 of
// a chunk is a dense 1024B sweep = conflict-free.

typedef __attribute__((ext_vector_type(8))) short bf16x8;
typedef __attribute__((ext_vector_type(4))) float f32x4;

// LDS layout (bytes)
#define LDS_A0 0                    // 16 rows x 256B  = 4096
#define LDS_A1 4096                 // 16 rows x 512B  = 8192
#define LDS_A2 12288                // 16 rows x 512B  = 8192
#define LDS_CB 20480                // 16 x float4     = 256
#define LDS_B  21504                // 16 waves x 2 slots x 4096 = 131072
#define LDS_TOT (21504 + 131072)    // 152576 < 160K

#define VMW4()  asm volatile("s_waitcnt vmcnt(4)" ::: "memory")
#define VMW0()  asm volatile("s_waitcnt vmcnt(0)" ::: "memory")
#define LGKM0() asm volatile("s_waitcnt lgkmcnt(0)" ::: "memory")

static __device__ __forceinline__ void bar_keep_vmcnt() {
  asm volatile("s_waitcnt lgkmcnt(0)" ::: "memory");
  __builtin_amdgcn_s_barrier();
  asm volatile("" ::: "memory");
}

typedef const __attribute__((address_space(1))) unsigned char* gp1_t;
typedef __attribute__((address_space(3))) unsigned char* lp3_t;
static __device__ __forceinline__ void gl_lds16(const void* g, void* l) {
  __builtin_amdgcn_global_load_lds((gp1_t)g, (lp3_t)l, 16, 0, 0);
}

// stage one K=32 chunk (4 anchors x 1KB) of this wave's 16 columns.
// sb = per-lane source base: Wt + (colbase + (lane>>2))*ROWLEN + (lane&3)*8
// dst layout: [k][lane*16] ; lane covers (colL=lane>>2, qs=lane&3)
#define STAGE(sb, KIN, ci, slot) do {                                  \
    const unsigned short* _s = (sb) + (ci) * 32;                       \
    char* _d = myB + (slot) * 4096;                                    \
    gl_lds16(_s,             _d);                                      \
    gl_lds16(_s + (KIN),     _d + 1024);                               \
    gl_lds16(_s + 2 * (KIN), _d + 2048);                               \
    gl_lds16(_s + 3 * (KIN), _d + 3072);                               \
  } while (0)

static __device__ __forceinline__ unsigned short f2bf(float f) {
  union { float f; unsigned int u; } v; v.f = f;
  unsigned int r = v.u + 0x7fffu + ((v.u >> 16) & 1u);  // RNE
  return (unsigned short)(r >> 16);
}

// Catmull-Rom basis coeffs in ABSOLUTE anchor order (c[0..3] for anchors 0..3)
static __device__ __forceinline__ void catmull(float ph, float c[4]) {
  float t = 4.0f * ph;
  float ft = floorf(t);
  int i1 = ((int)ft) & 3;
  float w = t - ft;
  float w2 = w * w, w3 = w2 * w;
  float r0 = -0.5f * w + w2 - 0.5f * w3;
  float r1 = 1.0f - 2.5f * w2 + 1.5f * w3;
  float r2 = 0.5f * w + 2.0f * w2 - 1.5f * w3;
  float r3 = -0.5f * w2 + 0.5f * w3;
  c[(i1 + 3) & 3] = r0;
  c[i1]           = r1;
  c[(i1 + 1) & 3] = r2;
  c[(i1 + 2) & 3] = r3;
}

// ---------------------------------------------------------------------------
// Prep: transpose+convert all three weight tensors (fp32 [4K,O] -> bf16 [O,4K])
// ---------------------------------------------------------------------------
__global__ void k_wt_all(const float* __restrict__ w0, const float* __restrict__ w1,
                         const float* __restrict__ w2, unsigned short* __restrict__ t0,
                         unsigned short* __restrict__ t1, unsigned short* __restrict__ t2) {
  __shared__ float tile[32][33];
  int bid = blockIdx.x;
  const float* W; unsigned short* T; int R, C, idx;
  if (bid < 128)      { W = w0; T = t0; R = 512;  C = 256; idx = bid; }
  else if (bid < 384) { W = w1; T = t1; R = 1024; C = 256; idx = bid - 128; }
  else                { W = w2; T = t2; R = 1024; C = 128; idx = bid - 384; }
  int ntc = C >> 5;
  int tr = (idx / ntc) << 5;
  int tc = (idx % ntc) << 5;
  int tx = threadIdx.x, ty = threadIdx.y;  // (32,8)
#pragma unroll
  for (int j = ty; j < 32; j += 8)
    tile[j][tx] = W[(size_t)(tr + j) * C + (tc + tx)];
  __syncthreads();
#pragma unroll
  for (int j = ty; j < 32; j += 8)
    T[(size_t)(tc + j) * R + (tr + tx)] = f2bf(tile[tx][j]);
}

// mid-layer epilogue: anchor-combine + bias + ELU, one bf16 write per (row,col)
static __device__ __forceinline__ void epi_mid(f32x4 a0, f32x4 a1, f32x4 a2, f32x4 a3,
                                               const float bv[4], const float* cbf,
                                               int colg, int quad, char* outBuf) {
  const int g = colg >> 3;
  const int j2 = (colg & 7) * 2;
#pragma unroll
  for (int r = 0; r < 4; ++r) {
    const int m = quad * 4 + r;
    const float4 c = *(const float4*)(cbf + m * 4);
    float y = c.x * (a0[r] + bv[0]) + c.y * (a1[r] + bv[1]) +
              c.z * (a2[r] + bv[2]) + c.w * (a3[r] + bv[3]);
    float a = y > 0.0f ? y : (__expf(y) - 1.0f);  // ELU
    *(unsigned short*)(outBuf + m * 512 + (((g ^ (m & 15)) << 4) + j2)) = f2bf(a);
  }
}

#define MFMA4()                                                            \
  acc0 = __builtin_amdgcn_mfma_f32_16x16x32_bf16(av, bv0, acc0, 0, 0, 0);  \
  acc1 = __builtin_amdgcn_mfma_f32_16x16x32_bf16(av, bv1, acc1, 0, 0, 0);  \
  acc2 = __builtin_amdgcn_mfma_f32_16x16x32_bf16(av, bv2, acc2, 0, 0, 0);  \
  acc3 = __builtin_amdgcn_mfma_f32_16x16x32_bf16(av, bv3, acc3, 0, 0, 0)

#define LOADB()                                                \
  bf16x8 bv0 = *(const bf16x8*)(bs + bOff);                    \
  bf16x8 bv1 = *(const bf16x8*)(bs + 1024 + bOff);             \
  bf16x8 bv2 = *(const bf16x8*)(bs + 2048 + bOff);             \
  bf16x8 bv3 = *(const bf16x8*)(bs + 3072 + bOff)

__global__ __launch_bounds__(1024, 4) void k_fused(
    const float* __restrict__ x, const float* __restrict__ phase,
    const unsigned short* __restrict__ Wt0, const float* __restrict__ b0,
    const unsigned short* __restrict__ Wt1, const float* __restrict__ b1,
    const unsigned short* __restrict__ Wt2, const float* __restrict__ b2,
    float* __restrict__ out) {
  __shared__ __align__(1024) char smem[LDS_TOT];

  const int tid = threadIdx.x;
  const int lane = tid & 63;
  const int wid = tid >> 6;     // 0..15
  const int col = lane & 15;    // MFMA row-of-A / col-of-B lane index
  const int quad = lane >> 4;
  const int m0 = blockIdx.x * 16;
  const int colg = wid * 16 + col;           // L0/L1 output column
  const int cg = wid & 7, kh = wid >> 3;     // L2: col-group + K-half
  const int colg2 = cg * 16 + col;
  const int hi16 = (col & 12) << 4;          // A-swizzle high bits
  const int lb = (quad ^ (col & 3)) << 4;    // A-swizzle low bits
  const int bOff = col * 64 + quad * 16;     // B chunk read offset (dense)

  char* myB = smem + LDS_B + wid * 8192;
  float* cbf = (float*)(smem + LDS_CB);

  // per-lane staged-source bases (lane covers colL=lane>>2, qs=lane&3)
  const int colL = lane >> 2, qs = lane & 3;
  const unsigned short* sb0 = Wt0 + (size_t)(wid * 16 + colL) * 512 + qs * 8;
  const unsigned short* sb1 = Wt1 + (size_t)(wid * 16 + colL) * 1024 + qs * 8;
  const unsigned short* sb2 = Wt2 + (size_t)(cg * 16 + colL) * 1024 + kh * 128 + qs * 8;

  // ---- issue x load first (so compiler's x-wait is counted, not vmcnt(0)) ----
  float4 xv = {0.f, 0.f, 0.f, 0.f};
  if (tid < 512)
    xv = *(const float4*)(x + (size_t)(m0 + (tid >> 5)) * 128 + (tid & 31) * 4);

  // biases (issued before the staging stream)
  float bva[4], bvb[4], bvc[4];
#pragma unroll
  for (int k = 0; k < 4; ++k) {
    bva[k] = b0[k * 256 + colg];
    bvb[k] = b1[k * 256 + colg];
    bvc[k] = b2[k * 128 + colg2];
  }

  // Catmull coeff table (16 rows)
  if (tid < 16) {
    float c[4];
    catmull(phase[m0 + tid], c);
    cbf[tid * 4 + 0] = c[0]; cbf[tid * 4 + 1] = c[1];
    cbf[tid * 4 + 2] = c[2]; cbf[tid * 4 + 3] = c[3];
  }

  // ---- prologue: stage L0 chunks 0,1 (stream stays ahead from here on) ----
  STAGE(sb0, 128, 0, 0);
  STAGE(sb0, 128, 1, 1);

  // ---- build A0: unscaled bf16 x, granule-swizzled (g ^ (row&15)) ----
  if (tid < 512) {
    const int row = tid >> 5, seg = tid & 31;
    const int g = seg >> 1, h = seg & 1;
    short4 hv;
    hv.x = (short)f2bf(xv.x); hv.y = (short)f2bf(xv.y);
    hv.z = (short)f2bf(xv.z); hv.w = (short)f2bf(xv.w);
    *(short4*)(smem + LDS_A0 + row * 256 + ((g ^ (row & 15)) << 4) + h * 8) = hv;
  }
  bar_keep_vmcnt();

  f32x4 acc0, acc1, acc2, acc3;

  // ---- layer 0: A0 (K=128 x 4 anchors) @ Wt0 -> A1 ----
  {
    acc0 = acc1 = acc2 = acc3 = (f32x4){0.f, 0.f, 0.f, 0.f};
    const char* aL = smem + LDS_A0 + col * 256 + lb;
#pragma unroll
    for (int i = 0; i < 4; ++i) {
      VMW4();
      const char* bs = myB + (i & 1) * 4096;
      bf16x8 av = *(const bf16x8*)(aL + ((i << 6) ^ hi16));
      LOADB();
      LGKM0();                       // reads in regs -> safe to overwrite slot
      if (i == 0)      STAGE(sb0, 128, 2, 0);
      else if (i == 1) STAGE(sb0, 128, 3, 1);
      else if (i == 2) STAGE(sb1, 256, 0, 0);   // cross-layer prefetch
      else             STAGE(sb1, 256, 1, 1);
      MFMA4();
    }
    epi_mid(acc0, acc1, acc2, acc3, bva, cbf, colg, quad, smem + LDS_A1);
  }
  bar_keep_vmcnt();

  // ---- layer 1: A1 (K=256 x 4 anchors) @ Wt1 -> A2 ----
  {
    acc0 = acc1 = acc2 = acc3 = (f32x4){0.f, 0.f, 0.f, 0.f};
    const char* aL = smem + LDS_A1 + col * 512 + lb;
#pragma unroll
    for (int i = 0; i < 8; ++i) {
      VMW4();
      const char* bs = myB + (i & 1) * 4096;
      bf16x8 av = *(const bf16x8*)(aL + ((i << 6) ^ hi16));
      LOADB();
      LGKM0();
      if (i < 6)       STAGE(sb1, 256, i + 2, i & 1);
      else if (i == 6) STAGE(sb2, 256, 0, 0);   // cross-layer prefetch
      else             STAGE(sb2, 256, 1, 1);
      MFMA4();
    }
    epi_mid(acc0, acc1, acc2, acc3, bvb, cbf, colg, quad, smem + LDS_A2);
  }
  bar_keep_vmcnt();

  // ---- layer 2: A2 (K=256 x 4 anchors) @ Wt2 -> out fp32 (8 colgrp x 2 kh) ----
  {
    acc0 = acc1 = acc2 = acc3 = (f32x4){0.f, 0.f, 0.f, 0.f};
    const char* aL = smem + LDS_A2 + col * 512 + kh * 256 + lb;
#pragma unroll
    for (int i = 0; i < 4; ++i) {
      if (i < 3) { VMW4(); } else { VMW0(); }
      const char* bs = myB + (i & 1) * 4096;
      bf16x8 av = *(const bf16x8*)(aL + ((i << 6) ^ hi16));
      LOADB();
      if (i < 2) {
        LGKM0();
        if (i == 0) STAGE(sb2, 256, 2, 0);
        else        STAGE(sb2, 256, 3, 1);
      }
      MFMA4();
    }

    // anchor-combine partials
    float part[4];
#pragma unroll
    for (int r = 0; r < 4; ++r) {
      const int m = quad * 4 + r;
      const float4 c = *(const float4*)(cbf + m * 4);
      part[r] = c.x * acc0[r] + c.y * acc1[r] + c.z * acc2[r] + c.w * acc3[r];
    }

    // all waves past their Bst reads -> safe to overlay reduce buffer on Bst
    bar_keep_vmcnt();
    float* red = (float*)(smem + LDS_B);   // [8][16][17] = 8704 B
    if (kh) {
#pragma unroll
      for (int r = 0; r < 4; ++r)
        red[cg * 272 + (quad * 4 + r) * 17 + col] = part[r];
    }
    bar_keep_vmcnt();
    if (!kh) {
#pragma unroll
      for (int r = 0; r < 4; ++r) {
        const int m = quad * 4 + r;
        const float4 c = *(const float4*)(cbf + m * 4);
        float y = part[r] + red[cg * 272 + m * 17 + col] +
                  c.x * bvc[0] + c.y * bvc[1] + c.z * bvc[2] + c.w * bvc[3];
        out[(size_t)(m0 + m) * 128 + colg2] = y;
      }
    }
  }
}

// ---------------------------------------------------------------------------
// ws layout: Wt0 @0 (256KB), Wt1 @256KB (512KB), Wt2 @768KB (256KB). 1 MB.
// ---------------------------------------------------------------------------
extern "C" void kernel_launch(void* const* d_in, const int* in_sizes, int n_in,
                              void* d_out, int out_size, void* d_ws, size_t ws_size,
                              hipStream_t stream) {
  const float* x     = (const float*)d_in[0];
  const float* phase = (const float*)d_in[1];
  const float* w0    = (const float*)d_in[2];
  const float* b0    = (const float*)d_in[3];
  const float* w1    = (const float*)d_in[4];
  const float* b1    = (const float*)d_in[5];
  const float* w2    = (const float*)d_in[6];
  const float* b2    = (const float*)d_in[7];
  float* out = (float*)d_out;

  char* ws = (char*)d_ws;
  unsigned short* Wt0 = (unsigned short*)ws;
  unsigned short* Wt1 = (unsigned short*)(ws + 262144);
  unsigned short* Wt2 = (unsigned short*)(ws + 262144 + 524288);

  k_wt_all<<<512, dim3(32, 8), 0, stream>>>(w0, w1, w2, Wt0, Wt1, Wt2);
  k_fused<<<256, 1024, 0, stream>>>(x, phase, Wt0, b0, Wt1, b1, Wt2, b2, out);
}